// Round 10
// baseline (926.554 us; speedup 1.0000x reference)
//
#include <hip/hip_runtime.h>

#define BN_EPS 1e-5f
#define LN_EPS 1e-5f

typedef unsigned int uint;
typedef unsigned short ushort;
typedef __bf16 bf16_t;
typedef bf16_t bf16x8 __attribute__((ext_vector_type(8)));
typedef float f32x4 __attribute__((ext_vector_type(4)));

__device__ __forceinline__ float gelu_exact(float x){
    return 0.5f * x * (1.0f + erff(x * 0.7071067811865475f));
}
// tanh-approx GELU: max abs err vs exact ~1e-3 (well under threshold)
__device__ __forceinline__ float gelu_fast(float x){
    float z = x*(0.79788456f + 0.03567740814f*(x*x));
    z = fminf(fmaxf(z, -15.f), 15.f);
    float t = __builtin_amdgcn_exp2f(2.885390082f*z);   // e^{2z}
    return x*t*__builtin_amdgcn_rcpf(t + 1.0f);
}
__device__ __forceinline__ ushort f2bf(float f){
    union { float f; uint u; } x; x.f = f;
    uint r = (x.u + 0x7FFF + ((x.u >> 16) & 1)) >> 16;
    return (ushort)r;
}
__device__ __forceinline__ float bf2f(ushort u){
    union { uint u; float f; } x; x.u = ((uint)u) << 16;
    return x.f;
}

// ---------------- utility ----------------
__global__ void zero_i32(int* __restrict__ p, int n){
    int i = blockIdx.x*blockDim.x + threadIdx.x;
    if (i < n) p[i] = 0;
}
__global__ void zero_f32(float* __restrict__ p, int n){
    int i = blockIdx.x*blockDim.x + threadIdx.x;
    if (i < n) p[i] = 0.0f;
}

// input BN over 64 cols -> bf16, SPLIT-64 layout: 4 slices x 16 cols, [4][n][8 uints]
__global__ void bn_input(const float* __restrict__ x,
                         const float* __restrict__ g, const float* __restrict__ b,
                         const float* __restrict__ m, const float* __restrict__ v,
                         uint* __restrict__ outs, int n4, int n){
    int i = blockIdx.x*blockDim.x + threadIdx.x;
    if (i >= n4) return;
    int node = i >> 4;
    int c0 = (i & 15) * 4;
    float4 xv = ((const float4*)x)[i];
    ushort o[4];
    #pragma unroll
    for (int j = 0; j < 4; j++){
        int c = c0 + j;
        float s  = g[c] * rsqrtf(v[c] + BN_EPS);
        float sh = b[c] - m[c]*s;
        o[j] = f2bf((&xv.x)[j]*s + sh);
    }
    uint2 pk = make_uint2((uint)o[0] | ((uint)o[1]<<16), (uint)o[2] | ((uint)o[3]<<16));
    int cb = c0 >> 4;                        // slice (16 cols each)
    size_t pos = (size_t)cb*((size_t)n*8) + (size_t)node*8 + ((c0 & 15) >> 1);
    *(uint2*)(outs + pos) = pk;
}

// ---------------- weight packing into MFMA B-fragment order ----------------
__global__ void pack_w(const float* __restrict__ w, ushort* __restrict__ out, int K){
    int t = blockIdx.x*blockDim.x + threadIdx.x;
    int total = (K/32)*8*64;
    if (t >= total) return;
    int lane = t & 63;
    int rem = t >> 6;
    int nf = rem & 7;
    int kk = rem >> 3;
    int kg = lane >> 4;
    int col = nf*16 + (lane & 15);
    uint r[4];
    #pragma unroll
    for (int p = 0; p < 4; p++){
        int k0 = kk*32 + kg*8 + p*2;
        ushort lo = f2bf(w[(size_t)k0*128 + col]);
        ushort hi = f2bf(w[(size_t)(k0+1)*128 + col]);
        r[p] = (uint)lo | ((uint)hi << 16);
    }
    *(uint4*)(out + (size_t)t*8) = make_uint4(r[0], r[1], r[2], r[3]);
}

// ---------------- bucketed CSR build (dense writes) ----------------
// bucket = dst >> 8 (256 nodes per bucket), NB <= 1024 (N <= 262144)

__global__ __launch_bounds__(256) void bucket_count(const int* __restrict__ dst,
        int* __restrict__ bcnt, int E, int NB){
    __shared__ int h[1024];
    int tid = threadIdx.x;
    for (int i = tid; i < 1024; i += 256) h[i] = 0;
    __syncthreads();
    for (long i = (long)blockIdx.x*blockDim.x + tid; i < E; i += (long)gridDim.x*blockDim.x)
        atomicAdd(&h[dst[i] >> 8], 1);
    __syncthreads();
    for (int i = tid; i < NB; i += 256)
        if (h[i]) atomicAdd(&bcnt[i], h[i]);
}

__global__ __launch_bounds__(1024) void bucket_scan(const int* __restrict__ bcnt,
        int* __restrict__ boff, int* __restrict__ bcur, int NB, int E){
    __shared__ int s[1024];
    int tid = threadIdx.x;
    int v = (tid < NB) ? bcnt[tid] : 0;
    s[tid] = v; __syncthreads();
    for (int off = 1; off < 1024; off <<= 1){
        int t = s[tid];
        if (tid >= off) t += s[tid-off];
        __syncthreads(); s[tid] = t; __syncthreads();
    }
    if (tid < NB){ int ex = s[tid] - v; boff[tid] = ex; bcur[tid] = ex; }
    if (tid == 0) boff[NB] = E;
}

#define PCH 16384
// pack (dst_local<<24)|src into per-bucket contiguous runs
__global__ __launch_bounds__(512) void partition_kernel(const int* __restrict__ src,
        const int* __restrict__ dst, int* __restrict__ bcur,
        uint* __restrict__ pairs, int E, int NB){
    __shared__ ushort rnk[PCH];
    __shared__ int cnt[1024];
    __shared__ int base[1024];
    int tid = threadIdx.x;
    long chunk0 = (long)blockIdx.x * PCH;
    for (int i = tid; i < 1024; i += 512) cnt[i] = 0;
    __syncthreads();
    for (int k = 0; k < PCH/512; k++){
        int el = k*512 + tid;
        long i = chunk0 + el;
        if (i < E){
            int b = dst[i] >> 8;
            rnk[el] = (ushort)atomicAdd(&cnt[b], 1);
        }
    }
    __syncthreads();
    for (int b = tid; b < NB; b += 512)
        if (cnt[b] > 0) base[b] = atomicAdd(&bcur[b], cnt[b]);
    __syncthreads();
    for (int k = 0; k < PCH/512; k++){
        int el = k*512 + tid;
        long i = chunk0 + el;
        if (i < E){
            int d = dst[i];
            int b = d >> 8;
            int pos = base[b] + (int)rnk[el];
            pairs[pos] = ((uint)(d & 255) << 24) | (uint)src[i];
        }
    }
}

#define BCAP 12288
// one block per bucket: local degrees -> scan -> rowptr (coalesced),
// LDS scatter -> csrc streamed out coalesced
__global__ __launch_bounds__(256) void bucket_build(const uint* __restrict__ pairs,
        const int* __restrict__ boff, int* __restrict__ rowptr,
        int* __restrict__ csrc, int N, int E, int NB){
    __shared__ int deg[256];
    __shared__ int scn[256];
    __shared__ int cur[256];
    __shared__ uint outl[BCAP];
    int b = blockIdx.x, tid = threadIdx.x;
    int e0 = boff[b], e1 = boff[b+1];
    int M = e1 - e0;
    deg[tid] = 0;
    __syncthreads();
    for (int e = tid; e < M; e += 256){
        uint p = pairs[e0 + e];
        atomicAdd(&deg[p >> 24], 1);
    }
    __syncthreads();
    int v = deg[tid];
    scn[tid] = v; __syncthreads();
    for (int off = 1; off < 256; off <<= 1){
        int t = scn[tid];
        if (tid >= off) t += scn[tid-off];
        __syncthreads(); scn[tid] = t; __syncthreads();
    }
    int excl = scn[tid] - v;
    int node = b*256 + tid;
    if (node < N) rowptr[node] = e0 + excl;
    if (b == NB-1 && tid == 0) rowptr[N] = E;
    cur[tid] = excl;
    __syncthreads();
    if (M <= BCAP){
        for (int e = tid; e < M; e += 256){
            uint p = pairs[e0 + e];
            int lp = atomicAdd(&cur[p >> 24], 1);
            outl[lp] = p & 0x00FFFFFFu;
        }
        __syncthreads();
        for (int e = tid; e < M; e += 256)
            csrc[e0 + e] = (int)(outl[e]);
    } else {
        // fallback (unreachable for uniform dst): direct global scatter
        for (int e = tid; e < M; e += 256){
            uint p = pairs[e0 + e];
            int lp = atomicAdd(&cur[p >> 24], 1);
            csrc[e0 + lp] = (int)(p & 0x00FFFFFFu);
        }
    }
}

// ---------------- aggregation: XCD-sliced, wave-per-node, register accum ----------------
// h stored column-split (16 cols = 8 uints per slice) so each 3.2 MB slice fits one
// XCD L2; cb=blockIdx&(NS-1) rides blockIdx%8->XCD round-robin, pinning slice cb.
// Wave lanes = (edge slot u=lane>>3, col-pair c=lane&7). Gathers independent;
// accumulate in registers, reduce over u via shfl_xor, no LDS, no atomics.
// csrc streamed with nontemporal loads so it can't evict the hot slice.

// D=128: 8 slices x 16 cols; hs=[8][n][8 uints]; hout row-major [n][64 uints]
__global__ __launch_bounds__(256) void agg_s128(
        const uint* __restrict__ hs,
        const int* __restrict__ rowptr, const int* __restrict__ csrc,
        const float* __restrict__ epsp, int epsidx,
        uint* __restrict__ hout, int n)
{
    int cb = blockIdx.x & 7;
    int ng = blockIdx.x >> 3;
    int lane = threadIdx.x & 63;
    int wv = threadIdx.x >> 6;
    int u = lane >> 3;           // edge slot 0..7
    int c = lane & 7;            // col-pair 0..7
    float eps1 = 1.0f + epsp[epsidx];
    const uint* slice = hs + (size_t)cb * ((size_t)n * 8);
    int node0 = (ng*4 + wv) * 8;
    #pragma unroll 1
    for (int t = 0; t < 8; t++){
        int node = node0 + t;
        if (node >= n) return;                    // wave-uniform
        int beg = __builtin_amdgcn_readfirstlane(rowptr[node]);
        int end = __builtin_amdgcn_readfirstlane(rowptr[node+1]);
        float a0 = 0.f, a1 = 0.f;
        int j = beg;
        for (; j + 16 <= end; j += 16){           // two independent groups in flight
            int s0 = __builtin_nontemporal_load(&csrc[j + u]);
            int s1 = __builtin_nontemporal_load(&csrc[j + 8 + u]);
            uint t0 = slice[(size_t)s0*8 + c];
            uint t1 = slice[(size_t)s1*8 + c];
            a0 += bf2f((ushort)(t0 & 0xFFFF)); a1 += bf2f((ushort)(t0 >> 16));
            a0 += bf2f((ushort)(t1 & 0xFFFF)); a1 += bf2f((ushort)(t1 >> 16));
        }
        for (; j + 8 <= end; j += 8){
            int s0 = __builtin_nontemporal_load(&csrc[j + u]);
            uint t0 = slice[(size_t)s0*8 + c];
            a0 += bf2f((ushort)(t0 & 0xFFFF)); a1 += bf2f((ushort)(t0 >> 16));
        }
        if (j < end){
            int last = end - 1;
            int jj = j + u; jj = jj < last ? jj : last;
            int s0 = __builtin_nontemporal_load(&csrc[jj]);
            uint t0 = slice[(size_t)s0*8 + c];
            if (j + u < end){
                a0 += bf2f((ushort)(t0 & 0xFFFF)); a1 += bf2f((ushort)(t0 >> 16));
            }
        }
        #pragma unroll
        for (int m = 8; m <= 32; m <<= 1){
            a0 += __shfl_xor(a0, m, 64);
            a1 += __shfl_xor(a1, m, 64);
        }
        if (lane < 8){
            uint sv = slice[(size_t)node*8 + lane];
            float o0 = eps1*bf2f((ushort)(sv & 0xFFFF)) + a0;
            float o1 = eps1*bf2f((ushort)(sv >> 16))    + a1;
            hout[(size_t)node*64 + cb*8 + lane] = (uint)f2bf(o0) | ((uint)f2bf(o1) << 16);
        }
    }
}

// D=64: 4 slices x 16 cols; hs=[4][n][8 uints]; hout row-major [n][32 uints]
__global__ __launch_bounds__(256) void agg_s64(
        const uint* __restrict__ hs,
        const int* __restrict__ rowptr, const int* __restrict__ csrc,
        const float* __restrict__ epsp, int epsidx,
        uint* __restrict__ hout, int n)
{
    int cb = blockIdx.x & 3;
    int ng = blockIdx.x >> 2;
    int lane = threadIdx.x & 63;
    int wv = threadIdx.x >> 6;
    int u = lane >> 3;           // edge slot 0..7
    int c = lane & 7;            // col-pair 0..7
    float eps1 = 1.0f + epsp[epsidx];
    const uint* slice = hs + (size_t)cb * ((size_t)n * 8);
    int node0 = (ng*4 + wv) * 8;
    #pragma unroll 1
    for (int t = 0; t < 8; t++){
        int node = node0 + t;
        if (node >= n) return;                    // wave-uniform
        int beg = __builtin_amdgcn_readfirstlane(rowptr[node]);
        int end = __builtin_amdgcn_readfirstlane(rowptr[node+1]);
        float a0 = 0.f, a1 = 0.f;
        int j = beg;
        for (; j + 16 <= end; j += 16){
            int s0 = __builtin_nontemporal_load(&csrc[j + u]);
            int s1 = __builtin_nontemporal_load(&csrc[j + 8 + u]);
            uint t0 = slice[(size_t)s0*8 + c];
            uint t1 = slice[(size_t)s1*8 + c];
            a0 += bf2f((ushort)(t0 & 0xFFFF)); a1 += bf2f((ushort)(t0 >> 16));
            a0 += bf2f((ushort)(t1 & 0xFFFF)); a1 += bf2f((ushort)(t1 >> 16));
        }
        for (; j + 8 <= end; j += 8){
            int s0 = __builtin_nontemporal_load(&csrc[j + u]);
            uint t0 = slice[(size_t)s0*8 + c];
            a0 += bf2f((ushort)(t0 & 0xFFFF)); a1 += bf2f((ushort)(t0 >> 16));
        }
        if (j < end){
            int last = end - 1;
            int jj = j + u; jj = jj < last ? jj : last;
            int s0 = __builtin_nontemporal_load(&csrc[jj]);
            uint t0 = slice[(size_t)s0*8 + c];
            if (j + u < end){
                a0 += bf2f((ushort)(t0 & 0xFFFF)); a1 += bf2f((ushort)(t0 >> 16));
            }
        }
        #pragma unroll
        for (int m = 8; m <= 32; m <<= 1){
            a0 += __shfl_xor(a0, m, 64);
            a1 += __shfl_xor(a1, m, 64);
        }
        if (lane < 8){
            uint sv = slice[(size_t)node*8 + lane];
            float o0 = eps1*bf2f((ushort)(sv & 0xFFFF)) + a0;
            float o1 = eps1*bf2f((ushort)(sv >> 16))    + a1;
            hout[(size_t)node*32 + cb*8 + lane] = (uint)f2bf(o0) | ((uint)f2bf(o1) << 16);
        }
    }
}

// ---------------- fused MFMA MLP: Linear->BN->GELU->Linear->BN->GELU ----------------
// 128-row tile, 256 threads = 4 waves; wave wv owns rows [wv*32, wv*32+32).
// SPLIT_OUT: write split-128 layout [8][n][8 uints] (feeds sliced agg); else row-major.
template<int DIN, bool SPLIT_OUT>
__global__ __launch_bounds__(256) void mlp_mfma(
        const ushort* __restrict__ hin,
        const ushort* __restrict__ w1p, const float* __restrict__ b1,
        const float* __restrict__ g1, const float* __restrict__ bb1,
        const float* __restrict__ m1, const float* __restrict__ v1,
        const ushort* __restrict__ w2p, const float* __restrict__ b2,
        const float* __restrict__ g2, const float* __restrict__ bb2,
        const float* __restrict__ m2, const float* __restrict__ v2,
        ushort* __restrict__ hout, int n)
{
    constexpr int K1 = DIN/32;
    __shared__ ushort lds[128*128];         // 32 KiB: A1 -> h1 -> out
    __shared__ float mulA[128], addA[128], mulB[128], addB[128];
    int tid = threadIdx.x;
    int lane = tid & 63;
    int wv = tid >> 6;
    int row0 = blockIdx.x * 128;

    if (tid < 128){
        float s1 = g1[tid]*rsqrtf(v1[tid]+BN_EPS);
        mulA[tid] = s1; addA[tid] = (b1[tid]-m1[tid])*s1 + bb1[tid];
        float s2 = g2[tid]*rsqrtf(v2[tid]+BN_EPS);
        mulB[tid] = s2; addB[tid] = (b2[tid]-m2[tid])*s2 + bb2[tid];
    }

    // prefetch kk=0 weight fragments of GEMM1 (latency hides under staging)
    bf16x8 wpre[8];
    #pragma unroll
    for (int nf = 0; nf < 8; nf++)
        wpre[nf] = *(const bf16x8*)(w1p + ((size_t)(nf*64 + lane))*8);

    // stage A1 (128 x DIN bf16), zero-pad tail rows, XOR-swizzled
    constexpr int CPR = DIN/8;
    for (int idx = tid; idx < 128*CPR; idx += 256){
        int r = idx / CPR, c = idx - r*CPR;
        uint4 val = make_uint4(0,0,0,0);
        if (row0 + r < n) val = *(const uint4*)(hin + (size_t)(row0+r)*DIN + c*8);
        int byte = (r*DIN + c*8)*2 ^ ((r & 7) << 4);
        *(uint4*)((char*)lds + byte) = val;
    }
    __syncthreads();

    int r16 = lane & 15;
    int kg = lane >> 4;
    int arow = wv*32 + r16;                 // m=0 row; m=1 row = arow+16 (same &7)

    // GEMM1
    f32x4 acc[2][8];
    #pragma unroll
    for (int m = 0; m < 2; m++)
        #pragma unroll
        for (int nf = 0; nf < 8; nf++) acc[m][nf] = (f32x4){0.f,0.f,0.f,0.f};
    #pragma unroll
    for (int kk = 0; kk < K1; kk++){
        int ab0 = (arow*DIN + kk*32 + kg*8)*2 ^ ((arow & 7) << 4);
        bf16x8 a0 = *(const bf16x8*)((const char*)lds + ab0);
        bf16x8 a1 = *(const bf16x8*)((const char*)lds + ab0 + DIN*32);
        #pragma unroll
        for (int nf = 0; nf < 8; nf++){
            bf16x8 w = (kk == 0) ? wpre[nf]
                     : *(const bf16x8*)(w1p + ((size_t)((kk*8 + nf)*64 + lane))*8);
            acc[0][nf] = __builtin_amdgcn_mfma_f32_16x16x32_bf16(a0, w, acc[0][nf], 0, 0, 0);
            acc[1][nf] = __builtin_amdgcn_mfma_f32_16x16x32_bf16(a1, w, acc[1][nf], 0, 0, 0);
        }
    }

    if constexpr (DIN == 64) __syncthreads();   // h1 rows overlap other waves' A1 rows

    // prefetch kk=0 weight fragments of GEMM2
    bf16x8 wpre2[8];
    #pragma unroll
    for (int nf = 0; nf < 8; nf++)
        wpre2[nf] = *(const bf16x8*)(w2p + ((size_t)(nf*64 + lane))*8);

    // epilogue1: BN+GELU -> h1 in LDS [128][128] swizzled (wave-private rows)
    #pragma unroll
    for (int m = 0; m < 2; m++){
        #pragma unroll
        for (int nf = 0; nf < 8; nf++){
            int col = nf*16 + r16;
            float mu = mulA[col], ad = addA[col];
            #pragma unroll
            for (int r = 0; r < 4; r++){
                int row = wv*32 + m*16 + kg*4 + r;
                float xg = gelu_fast(acc[m][nf][r]*mu + ad);
                int byte = (row*128 + col)*2 ^ ((row & 7) << 4);
                *(ushort*)((char*)lds + byte) = f2bf(xg);
            }
        }
    }

    // GEMM2 (K = 128)
    f32x4 acc2[2][8];
    #pragma unroll
    for (int m = 0; m < 2; m++)
        #pragma unroll
        for (int nf = 0; nf < 8; nf++) acc2[m][nf] = (f32x4){0.f,0.f,0.f,0.f};
    #pragma unroll
    for (int kk = 0; kk < 4; kk++){
        int ab0 = (arow*128 + kk*32 + kg*8)*2 ^ ((arow & 7) << 4);
        bf16x8 a0 = *(const bf16x8*)((const char*)lds + ab0);
        bf16x8 a1 = *(const bf16x8*)((const char*)lds + ab0 + 128*32);
        #pragma unroll
        for (int nf = 0; nf < 8; nf++){
            bf16x8 w = (kk == 0) ? wpre2[nf]
                     : *(const bf16x8*)(w2p + ((size_t)((kk*8 + nf)*64 + lane))*8);
            acc2[0][nf] = __builtin_amdgcn_mfma_f32_16x16x32_bf16(a0, w, acc2[0][nf], 0, 0, 0);
            acc2[1][nf] = __builtin_amdgcn_mfma_f32_16x16x32_bf16(a1, w, acc2[1][nf], 0, 0, 0);
        }
    }

    // epilogue2: BN+GELU -> LDS (wave-private rows)
    #pragma unroll
    for (int m = 0; m < 2; m++){
        #pragma unroll
        for (int nf = 0; nf < 8; nf++){
            int col = nf*16 + r16;
            float mu = mulB[col], ad = addB[col];
            #pragma unroll
            for (int r = 0; r < 4; r++){
                int row = wv*32 + m*16 + kg*4 + r;
                float xg = gelu_fast(acc2[m][nf][r]*mu + ad);
                int byte = (row*128 + col)*2 ^ ((row & 7) << 4);
                *(ushort*)((char*)lds + byte) = f2bf(xg);
            }
        }
    }
    __syncthreads();

    // 16B stores: row-major or split-128 (2 chunks of 4 uints per 16-col slice)
    for (int idx = tid; idx < 128*16; idx += 256){
        int r = idx >> 4, cseg = idx & 15;
        if (row0 + r < n){
            int byte = (r*128 + cseg*8)*2 ^ ((r & 7) << 4);
            uint4 v = *(const uint4*)((const char*)lds + byte);
            if constexpr (SPLIT_OUT){
                int cb = cseg >> 1;
                size_t pos = (size_t)cb*((size_t)n*8) + (size_t)(row0+r)*8 + (cseg & 1)*4;
                *(uint4*)((uint*)hout + pos) = v;
            } else {
                *(uint4*)(hout + (size_t)(row0+r)*128 + cseg*8) = v;
            }
        }
    }
}

// ---------------- pooling (also accumulates per-graph node counts) ----------------
__global__ __launch_bounds__(128) void pool_kernel(const ushort* __restrict__ h,
        const int* __restrict__ batch, float* __restrict__ pool,
        float* __restrict__ cnt, int n){
    int c = threadIdx.x;
    int n0 = blockIdx.x * 32;
    float run = 0.f;
    float runc = 0.f;
    int curg = -1;
    for (int t = 0; t < 32; ++t){
        int node = n0 + t;
        if (node >= n) break;
        int gph = batch[node];
        if (gph != curg){
            if (curg >= 0){
                atomicAdd(&pool[curg*128 + c], run);
                if (c == 0) atomicAdd(&cnt[curg], runc);
            }
            curg = gph; run = 0.f; runc = 0.f;
        }
        run += bf2f(h[(size_t)node*128 + c]);
        runc += 1.f;
    }
    if (curg >= 0){
        atomicAdd(&pool[curg*128 + c], run);
        if (c == 0) atomicAdd(&cnt[curg], runc);
    }
}

// ---------------- head: fc1 -> LN -> GELU -> +res -> fc2 (f32, exact gelu) ----------------
__global__ __launch_bounds__(128) void head_kernel(const float* __restrict__ pool,
        const float* __restrict__ cnt,
        const float* __restrict__ fc1w, const float* __restrict__ fc1b,
        const float* __restrict__ lng, const float* __restrict__ lnb,
        const float* __restrict__ fc2w, const float* __restrict__ fc2b,
        float* __restrict__ out, int G){
    __shared__ float p[128];
    __shared__ float q[128];
    __shared__ float red[128];
    int g = blockIdx.x, c = threadIdx.x;
    float inv = 1.0f / fmaxf(cnt[g], 1.0f);
    float pv = pool[g*128 + c] * inv;
    p[c] = pv;
    __syncthreads();
    float o = fc1b[c];
    for (int k = 0; k < 128; k++) o = fmaf(p[k], fc1w[k*128 + c], o);
    red[c] = o; __syncthreads();
    for (int s = 64; s > 0; s >>= 1){ if (c < s) red[c] += red[c+s]; __syncthreads(); }
    float mu = red[0] * (1.0f/128.0f);
    __syncthreads();
    float d = o - mu;
    red[c] = d*d; __syncthreads();
    for (int s = 64; s > 0; s >>= 1){ if (c < s) red[c] += red[c+s]; __syncthreads(); }
    float var = red[0] * (1.0f/128.0f);
    __syncthreads();
    float xn = d * rsqrtf(var + LN_EPS) * lng[c] + lnb[c];
    float qv = gelu_exact(xn) + pv;
    q[c] = qv;
    __syncthreads();
    if (c < 64){
        float a = fc2b[c];
        for (int k = 0; k < 128; k++) a = fmaf(q[k], fc2w[k*64 + c], a);
        out[g*64 + c] = a;
    }
}

// ---------------- launch ----------------
extern "C" void kernel_launch(void* const* d_in, const int* in_sizes, int n_in,
                              void* d_out, int out_size, void* d_ws, size_t ws_size,
                              hipStream_t stream){
    const float* x     = (const float*)d_in[0];
    const int*   ei    = (const int*)d_in[1];
    const int*   batch = (const int*)d_in[2];
    const float* in_g  = (const float*)d_in[3];
    const float* in_b  = (const float*)d_in[4];
    const float* in_m  = (const float*)d_in[5];
    const float* in_v  = (const float*)d_in[6];
    const float* eps0  = (const float*)d_in[7];
    const float* c0_w1 = (const float*)d_in[8];
    const float* c0_b1 = (const float*)d_in[9];
    const float* c0_g  = (const float*)d_in[10];
    const float* c0_bb = (const float*)d_in[11];
    const float* c0_m  = (const float*)d_in[12];
    const float* c0_v  = (const float*)d_in[13];
    const float* c0_w2 = (const float*)d_in[14];
    const float* c0_b2 = (const float*)d_in[15];
    const float* bn0_g = (const float*)d_in[16];
    const float* bn0_b = (const float*)d_in[17];
    const float* bn0_m = (const float*)d_in[18];
    const float* bn0_v = (const float*)d_in[19];
    const float* epsR  = (const float*)d_in[20];
    const float* cR_w1 = (const float*)d_in[21];
    const float* cR_b1 = (const float*)d_in[22];
    const float* cR_g  = (const float*)d_in[23];
    const float* cR_bb = (const float*)d_in[24];
    const float* cR_m  = (const float*)d_in[25];
    const float* cR_v  = (const float*)d_in[26];
    const float* cR_w2 = (const float*)d_in[27];
    const float* cR_b2 = (const float*)d_in[28];
    const float* bnR_g = (const float*)d_in[29];
    const float* bnR_b = (const float*)d_in[30];
    const float* bnR_m = (const float*)d_in[31];
    const float* bnR_v = (const float*)d_in[32];
    const float* fc1_w = (const float*)d_in[33];
    const float* fc1_b = (const float*)d_in[34];
    const float* ln_g  = (const float*)d_in[35];
    const float* ln_b  = (const float*)d_in[36];
    const float* fc2_w = (const float*)d_in[37];
    const float* fc2_b = (const float*)d_in[38];

    const int N = in_sizes[0] / 64;
    const int E = in_sizes[1] / 2;
    const int G = out_size / 64;
    const int NB = (N + 255) >> 8;
    const int* srcp = ei;
    const int* dstp = ei + E;

    char* ws = (char*)d_ws;
    size_t off = 0;
    auto alloc = [&](size_t bytes)->char*{
        char* p = ws + off;
        off = (off + bytes + 255) & ~(size_t)255;
        return p;
    };
    ushort* bufA   = (ushort*)alloc((size_t)N*128*2);
    ushort* bufB   = (ushort*)alloc((size_t)N*128*2);
    int*    rowptr = (int*)   alloc((size_t)(N+1)*4);
    int*    csrc   = (int*)   alloc((size_t)E*4);
    uint*   pairs  = (uint*)  alloc((size_t)E*4);
    int*    bcnt   = (int*)   alloc((size_t)1025*4);
    int*    boff   = (int*)   alloc((size_t)1025*4);
    int*    bcur   = (int*)   alloc((size_t)1024*4);
    float*  pool   = (float*) alloc((size_t)G*128*4);
    float*  cnt    = (float*) alloc((size_t)G*4);
    ushort* pw0_1  = (ushort*)alloc((size_t)64*128*2);
    ushort* pw0_2  = (ushort*)alloc((size_t)128*128*2);
    ushort* pwR_1  = (ushort*)alloc((size_t)2*128*128*2);
    ushort* pwR_2  = (ushort*)alloc((size_t)2*128*128*2);
    (void)ws_size; (void)n_in;

    // pack weights into MFMA fragment order (bf16)
    pack_w<<<(1024 + 255)/256, 256, 0, stream>>>(c0_w1, pw0_1, 64);
    pack_w<<<(2048 + 255)/256, 256, 0, stream>>>(c0_w2, pw0_2, 128);
    for (int l = 0; l < 2; l++){
        pack_w<<<(2048 + 255)/256, 256, 0, stream>>>(cR_w1 + (size_t)l*128*128, pwR_1 + (size_t)l*128*128, 128);
        pack_w<<<(2048 + 255)/256, 256, 0, stream>>>(cR_w2 + (size_t)l*128*128, pwR_2 + (size_t)l*128*128, 128);
    }

    // bucketed CSR build
    zero_i32<<<(NB + 255)/256, 256, 0, stream>>>(bcnt, NB);
    bucket_count<<<1024, 256, 0, stream>>>(dstp, bcnt, E, NB);
    bucket_scan<<<1, 1024, 0, stream>>>(bcnt, boff, bcur, NB, E);
    partition_kernel<<<(E + PCH-1)/PCH, 512, 0, stream>>>(srcp, dstp, bcur, pairs, E, NB);
    bucket_build<<<NB, 256, 0, stream>>>(pairs, boff, rowptr, csrc, N, E, NB);

    // input BN -> bufA (split-64: 4 slices x 16 cols, [4][n][8 uints])
    bn_input<<<(N*16 + 255)/256, 256, 0, stream>>>(x, in_g, in_b, in_m, in_v,
                                                   (uint*)bufA, N*16, N);

    const int aggs64_blocks  = ((N + 31)/32)*4;
    const int aggs128_blocks = ((N + 31)/32)*8;
    const int mlp_blocks = (N + 127)/128;

    // layer 0: sliced agg (split-64 -> row-64); mlp -> split-128
    agg_s64<<<aggs64_blocks, 256, 0, stream>>>((const uint*)bufA, rowptr, csrc,
                                               eps0, 0, (uint*)bufB, N);
    mlp_mfma<64,true><<<mlp_blocks, 256, 0, stream>>>(bufB,
        pw0_1, c0_b1, c0_g, c0_bb, c0_m, c0_v,
        pw0_2, c0_b2, bn0_g, bn0_b, bn0_m, bn0_v, bufA, N);

    // layer 1: sliced agg (split-128 -> row-128); mlp -> split-128
    agg_s128<<<aggs128_blocks, 256, 0, stream>>>((const uint*)bufA, rowptr, csrc,
                                                 epsR, 0, (uint*)bufB, N);
    mlp_mfma<128,true><<<mlp_blocks, 256, 0, stream>>>(bufB,
        pwR_1, cR_b1, cR_g, cR_bb, cR_m, cR_v,
        pwR_2, cR_b2, bnR_g, bnR_b, bnR_m, bnR_v, bufA, N);

    // layer 2: sliced agg (split-128 -> row-128); mlp -> row-major (for pool)
    agg_s128<<<aggs128_blocks, 256, 0, stream>>>((const uint*)bufA, rowptr, csrc,
                                                 epsR, 1, (uint*)bufB, N);
    mlp_mfma<128,false><<<mlp_blocks, 256, 0, stream>>>(bufB,
        pwR_1 + (size_t)128*128, cR_b1 + 128, cR_g + 128, cR_bb + 128,
        cR_m + 128, cR_v + 128,
        pwR_2 + (size_t)128*128, cR_b2 + 128, bnR_g + 128, bnR_b + 128,
        bnR_m + 128, bnR_v + 128, bufA, N);

    // mean pool + head
    zero_f32<<<(G*128 + 255)/256, 256, 0, stream>>>(pool, G*128);
    zero_f32<<<(G + 255)/256, 256, 0, stream>>>(cnt, G);
    pool_kernel<<<(N + 31)/32, 128, 0, stream>>>(bufA, batch, pool, cnt, N);
    head_kernel<<<G, 128, 0, stream>>>(pool, cnt, fc1_w, fc1_b, ln_g, ln_b,
                                       fc2_w, fc2_b, (float*)d_out, G);
}

// Round 11
// 368.611 us; speedup vs baseline: 2.5136x; 2.5136x over previous
//
#include <hip/hip_runtime.h>

#define BN_EPS 1e-5f
#define LN_EPS 1e-5f

typedef unsigned int uint;
typedef unsigned short ushort;
typedef __bf16 bf16_t;
typedef bf16_t bf16x8 __attribute__((ext_vector_type(8)));
typedef float f32x4 __attribute__((ext_vector_type(4)));

__device__ __forceinline__ float gelu_exact(float x){
    return 0.5f * x * (1.0f + erff(x * 0.7071067811865475f));
}
// tanh-approx GELU: max abs err vs exact ~1e-3 (well under threshold)
__device__ __forceinline__ float gelu_fast(float x){
    float z = x*(0.79788456f + 0.03567740814f*(x*x));
    z = fminf(fmaxf(z, -15.f), 15.f);
    float t = __builtin_amdgcn_exp2f(2.885390082f*z);   // e^{2z}
    return x*t*__builtin_amdgcn_rcpf(t + 1.0f);
}
__device__ __forceinline__ ushort f2bf(float f){
    union { float f; uint u; } x; x.f = f;
    uint r = (x.u + 0x7FFF + ((x.u >> 16) & 1)) >> 16;
    return (ushort)r;
}
__device__ __forceinline__ float bf2f(ushort u){
    union { uint u; float f; } x; x.u = ((uint)u) << 16;
    return x.f;
}

// ---------------- utility ----------------
__global__ void zero_i32(int* __restrict__ p, int n){
    int i = blockIdx.x*blockDim.x + threadIdx.x;
    if (i < n) p[i] = 0;
}
__global__ void zero_f32(float* __restrict__ p, int n){
    int i = blockIdx.x*blockDim.x + threadIdx.x;
    if (i < n) p[i] = 0.0f;
}

// input BN over 64 cols -> bf16 (row-major)
__global__ void bn_input(const float* __restrict__ x,
                         const float* __restrict__ g, const float* __restrict__ b,
                         const float* __restrict__ m, const float* __restrict__ v,
                         ushort* __restrict__ out, int n4){
    int i = blockIdx.x*blockDim.x + threadIdx.x;
    if (i >= n4) return;
    int c0 = (i & 15) * 4;
    float4 xv = ((const float4*)x)[i];
    ushort o[4];
    #pragma unroll
    for (int j = 0; j < 4; j++){
        int c = c0 + j;
        float s  = g[c] * rsqrtf(v[c] + BN_EPS);
        float sh = b[c] - m[c]*s;
        o[j] = f2bf((&xv.x)[j]*s + sh);
    }
    uint2 pk = make_uint2((uint)o[0] | ((uint)o[1]<<16), (uint)o[2] | ((uint)o[3]<<16));
    ((uint2*)out)[i] = pk;
}

// ---------------- weight packing into MFMA B-fragment order ----------------
__global__ void pack_w(const float* __restrict__ w, ushort* __restrict__ out, int K){
    int t = blockIdx.x*blockDim.x + threadIdx.x;
    int total = (K/32)*8*64;
    if (t >= total) return;
    int lane = t & 63;
    int rem = t >> 6;
    int nf = rem & 7;
    int kk = rem >> 3;
    int kg = lane >> 4;
    int col = nf*16 + (lane & 15);
    uint r[4];
    #pragma unroll
    for (int p = 0; p < 4; p++){
        int k0 = kk*32 + kg*8 + p*2;
        ushort lo = f2bf(w[(size_t)k0*128 + col]);
        ushort hi = f2bf(w[(size_t)(k0+1)*128 + col]);
        r[p] = (uint)lo | ((uint)hi << 16);
    }
    *(uint4*)(out + (size_t)t*8) = make_uint4(r[0], r[1], r[2], r[3]);
}

// ---------------- bucketed CSR build (dense writes) ----------------
// bucket = dst >> 8 (256 nodes per bucket), NB <= 1024 (N <= 262144)

__global__ __launch_bounds__(256) void bucket_count(const int* __restrict__ dst,
        int* __restrict__ bcnt, int E, int NB){
    __shared__ int h[1024];
    int tid = threadIdx.x;
    for (int i = tid; i < 1024; i += 256) h[i] = 0;
    __syncthreads();
    for (long i = (long)blockIdx.x*blockDim.x + tid; i < E; i += (long)gridDim.x*blockDim.x)
        atomicAdd(&h[dst[i] >> 8], 1);
    __syncthreads();
    for (int i = tid; i < NB; i += 256)
        if (h[i]) atomicAdd(&bcnt[i], h[i]);
}

__global__ __launch_bounds__(1024) void bucket_scan(const int* __restrict__ bcnt,
        int* __restrict__ boff, int* __restrict__ bcur, int NB, int E){
    __shared__ int s[1024];
    int tid = threadIdx.x;
    int v = (tid < NB) ? bcnt[tid] : 0;
    s[tid] = v; __syncthreads();
    for (int off = 1; off < 1024; off <<= 1){
        int t = s[tid];
        if (tid >= off) t += s[tid-off];
        __syncthreads(); s[tid] = t; __syncthreads();
    }
    if (tid < NB){ int ex = s[tid] - v; boff[tid] = ex; bcur[tid] = ex; }
    if (tid == 0) boff[NB] = E;
}

#define PCH 16384
// pack (dst_local<<24)|src into per-bucket contiguous runs
__global__ __launch_bounds__(512) void partition_kernel(const int* __restrict__ src,
        const int* __restrict__ dst, int* __restrict__ bcur,
        uint* __restrict__ pairs, int E, int NB){
    __shared__ ushort rnk[PCH];
    __shared__ int cnt[1024];
    __shared__ int base[1024];
    int tid = threadIdx.x;
    long chunk0 = (long)blockIdx.x * PCH;
    for (int i = tid; i < 1024; i += 512) cnt[i] = 0;
    __syncthreads();
    for (int k = 0; k < PCH/512; k++){
        int el = k*512 + tid;
        long i = chunk0 + el;
        if (i < E){
            int b = dst[i] >> 8;
            rnk[el] = (ushort)atomicAdd(&cnt[b], 1);
        }
    }
    __syncthreads();
    for (int b = tid; b < NB; b += 512)
        if (cnt[b] > 0) base[b] = atomicAdd(&bcur[b], cnt[b]);
    __syncthreads();
    for (int k = 0; k < PCH/512; k++){
        int el = k*512 + tid;
        long i = chunk0 + el;
        if (i < E){
            int d = dst[i];
            int b = d >> 8;
            int pos = base[b] + (int)rnk[el];
            pairs[pos] = ((uint)(d & 255) << 24) | (uint)src[i];
        }
    }
}

#define BCAP 12288
// one block per bucket: local degrees -> scan -> rowptr (coalesced),
// LDS scatter -> csrc streamed out coalesced
__global__ __launch_bounds__(256) void bucket_build(const uint* __restrict__ pairs,
        const int* __restrict__ boff, int* __restrict__ rowptr,
        int* __restrict__ csrc, int N, int E, int NB){
    __shared__ int deg[256];
    __shared__ int scn[256];
    __shared__ int cur[256];
    __shared__ uint outl[BCAP];
    int b = blockIdx.x, tid = threadIdx.x;
    int e0 = boff[b], e1 = boff[b+1];
    int M = e1 - e0;
    deg[tid] = 0;
    __syncthreads();
    for (int e = tid; e < M; e += 256){
        uint p = pairs[e0 + e];
        atomicAdd(&deg[p >> 24], 1);
    }
    __syncthreads();
    int v = deg[tid];
    scn[tid] = v; __syncthreads();
    for (int off = 1; off < 256; off <<= 1){
        int t = scn[tid];
        if (tid >= off) t += scn[tid-off];
        __syncthreads(); scn[tid] = t; __syncthreads();
    }
    int excl = scn[tid] - v;
    int node = b*256 + tid;
    if (node < N) rowptr[node] = e0 + excl;
    if (b == NB-1 && tid == 0) rowptr[N] = E;
    cur[tid] = excl;
    __syncthreads();
    if (M <= BCAP){
        for (int e = tid; e < M; e += 256){
            uint p = pairs[e0 + e];
            int lp = atomicAdd(&cur[p >> 24], 1);
            outl[lp] = p & 0x00FFFFFFu;
        }
        __syncthreads();
        for (int e = tid; e < M; e += 256)
            csrc[e0 + e] = (int)(outl[e]);
    } else {
        // fallback (unreachable for uniform dst): direct global scatter
        for (int e = tid; e < M; e += 256){
            uint p = pairs[e0 + e];
            int lp = atomicAdd(&cur[p >> 24], 1);
            csrc[e0 + lp] = (int)(p & 0x00FFFFFFu);
        }
    }
}

// ---------------- aggregation: one wave per node, 16-wide gather groups ----------------
// (round-8 proven version: scalarized metadata, row gathers, 16 in flight)
__global__ __launch_bounds__(256) void agg_d64(const ushort* __restrict__ hin,
        const int* __restrict__ rowptr, const int* __restrict__ csrc,
        const float* __restrict__ epsp, int epsidx,
        ushort* __restrict__ hout, int n){
    int w = __builtin_amdgcn_readfirstlane(blockIdx.x*4 + (threadIdx.x >> 6));
    if (w >= n) return;
    int lane = threadIdx.x & 63;
    float eps1 = 1.0f + epsp[epsidx];
    int beg = __builtin_amdgcn_readfirstlane(rowptr[w]);
    int end = __builtin_amdgcn_readfirstlane(rowptr[w+1]);
    float acc = 0.0f;
    int j = beg;
    for (; j + 16 <= end; j += 16){
        ushort t[16];
        #pragma unroll
        for (int u = 0; u < 16; u++){
            int su = __builtin_amdgcn_readfirstlane(csrc[j+u]);
            t[u] = hin[((size_t)su << 6) + lane];
        }
        #pragma unroll
        for (int u = 0; u < 16; u++) acc += bf2f(t[u]);
    }
    if (j < end){
        int last = end - 1;
        ushort t[16];
        #pragma unroll
        for (int u = 0; u < 16; u++){
            int jj = j + u; jj = jj < last ? jj : last;
            int su = __builtin_amdgcn_readfirstlane(csrc[jj]);
            t[u] = hin[((size_t)su << 6) + lane];
        }
        #pragma unroll
        for (int u = 0; u < 16; u++){
            ushort tv = (j + u) < end ? t[u] : (ushort)0;
            acc += bf2f(tv);
        }
    }
    float self = bf2f(hin[((size_t)w << 6) + lane]);
    hout[((size_t)w << 6) + lane] = f2bf(eps1*self + acc);
}

__global__ __launch_bounds__(256) void agg_d128(const ushort* __restrict__ hin,
        const int* __restrict__ rowptr, const int* __restrict__ csrc,
        const float* __restrict__ epsp, int epsidx,
        ushort* __restrict__ hout, int n){
    int w = __builtin_amdgcn_readfirstlane(blockIdx.x*4 + (threadIdx.x >> 6));
    if (w >= n) return;
    int lane = threadIdx.x & 63;
    float eps1 = 1.0f + epsp[epsidx];
    int beg = __builtin_amdgcn_readfirstlane(rowptr[w]);
    int end = __builtin_amdgcn_readfirstlane(rowptr[w+1]);
    const uint* h2 = (const uint*)hin;
    float ax = 0.f, ay = 0.f;
    int j = beg;
    for (; j + 16 <= end; j += 16){
        uint t[16];
        #pragma unroll
        for (int u = 0; u < 16; u++){
            int su = __builtin_amdgcn_readfirstlane(csrc[j+u]);
            t[u] = h2[((size_t)su << 6) + lane];
        }
        #pragma unroll
        for (int u = 0; u < 16; u++){
            ax += bf2f((ushort)(t[u] & 0xFFFF));
            ay += bf2f((ushort)(t[u] >> 16));
        }
    }
    if (j < end){
        int last = end - 1;
        uint t[16];
        #pragma unroll
        for (int u = 0; u < 16; u++){
            int jj = j + u; jj = jj < last ? jj : last;
            int su = __builtin_amdgcn_readfirstlane(csrc[jj]);
            t[u] = h2[((size_t)su << 6) + lane];
        }
        #pragma unroll
        for (int u = 0; u < 16; u++){
            uint tv = (j + u) < end ? t[u] : 0u;
            ax += bf2f((ushort)(tv & 0xFFFF));
            ay += bf2f((ushort)(tv >> 16));
        }
    }
    uint c = h2[((size_t)w << 6) + lane];
    float ox = eps1*bf2f((ushort)(c & 0xFFFF)) + ax;
    float oy = eps1*bf2f((ushort)(c >> 16)) + ay;
    ((uint*)hout)[((size_t)w << 6) + lane] = (uint)f2bf(ox) | ((uint)f2bf(oy) << 16);
}

// ---------------- fused MFMA MLP: Linear->BN->GELU->Linear->BN->GELU ----------------
// 128-row tile, 256 threads = 4 waves; wave wv owns rows [wv*32, wv*32+32).
// A-tile staging via global_load_lds width=16 (direct HBM->LDS, no VGPR round-trip).
// LDS is linear; the XOR swizzle is applied on the SOURCE side (rule #21):
// linear LDS chunk (r, cl) receives source chunk (r, cl ^ (r&7)), so LDS content is
// byte-identical to the previous ds_write path and the read side is unchanged.
template<int DIN>
__global__ __launch_bounds__(256) void mlp_mfma(
        const ushort* __restrict__ hin,
        const ushort* __restrict__ w1p, const float* __restrict__ b1,
        const float* __restrict__ g1, const float* __restrict__ bb1,
        const float* __restrict__ m1, const float* __restrict__ v1,
        const ushort* __restrict__ w2p, const float* __restrict__ b2,
        const float* __restrict__ g2, const float* __restrict__ bb2,
        const float* __restrict__ m2, const float* __restrict__ v2,
        ushort* __restrict__ hout, int n)
{
    constexpr int K1 = DIN/32;
    __shared__ ushort lds[128*128];         // 32 KiB: A1 -> h1 -> out
    __shared__ float mulA[128], addA[128], mulB[128], addB[128];
    int tid = threadIdx.x;
    int lane = tid & 63;
    int wv = tid >> 6;
    int row0 = blockIdx.x * 128;

    if (tid < 128){
        float s1 = g1[tid]*rsqrtf(v1[tid]+BN_EPS);
        mulA[tid] = s1; addA[tid] = (b1[tid]-m1[tid])*s1 + bb1[tid];
        float s2 = g2[tid]*rsqrtf(v2[tid]+BN_EPS);
        mulB[tid] = s2; addB[tid] = (b2[tid]-m2[tid])*s2 + bb2[tid];
    }

    // prefetch kk=0 weight fragments of GEMM1 (latency hides under staging)
    bf16x8 wpre[8];
    #pragma unroll
    for (int nf = 0; nf < 8; nf++)
        wpre[nf] = *(const bf16x8*)(w1p + ((size_t)(nf*64 + lane))*8);

    // stage A1 (128 x DIN bf16), source-side swizzle
    constexpr int CPR = DIN/8;   // 16B chunks per row
    if (row0 + 128 <= n){
        #pragma unroll
        for (int base = 0; base < 128*CPR; base += 256){
            int idx = base + tid;                 // chunk index; contiguous per wave
            int r  = idx / CPR;
            int cl = idx - r*CPR;
            int cs = cl ^ (r & 7);                // source chunk (XOR swizzle)
            const void* gp = (const void*)(hin + (size_t)(row0 + r)*DIN + cs*8);
            char* lp = (char*)lds + (size_t)(base + wv*64)*16;   // wave-uniform base
            __builtin_amdgcn_global_load_lds(
                (const __attribute__((address_space(1))) void*)gp,
                (__attribute__((address_space(3))) void*)lp,
                16, 0, 0);
        }
    } else {
        for (int idx = tid; idx < 128*CPR; idx += 256){
            int r = idx / CPR, cl = idx - r*CPR;
            int cs = cl ^ (r & 7);
            uint4 val = make_uint4(0,0,0,0);
            if (row0 + r < n) val = *(const uint4*)(hin + (size_t)(row0+r)*DIN + cs*8);
            *(uint4*)((char*)lds + (size_t)idx*16) = val;
        }
    }
    __syncthreads();

    int r16 = lane & 15;
    int kg = lane >> 4;
    int arow = wv*32 + r16;                 // m=0 row; m=1 row = arow+16 (same &7)

    // GEMM1
    f32x4 acc[2][8];
    #pragma unroll
    for (int m = 0; m < 2; m++)
        #pragma unroll
        for (int nf = 0; nf < 8; nf++) acc[m][nf] = (f32x4){0.f,0.f,0.f,0.f};
    #pragma unroll
    for (int kk = 0; kk < K1; kk++){
        int ab0 = (arow*DIN + kk*32 + kg*8)*2 ^ ((arow & 7) << 4);
        bf16x8 a0 = *(const bf16x8*)((const char*)lds + ab0);
        bf16x8 a1 = *(const bf16x8*)((const char*)lds + ab0 + DIN*32);
        #pragma unroll
        for (int nf = 0; nf < 8; nf++){
            bf16x8 w = (kk == 0) ? wpre[nf]
                     : *(const bf16x8*)(w1p + ((size_t)((kk*8 + nf)*64 + lane))*8);
            acc[0][nf] = __builtin_amdgcn_mfma_f32_16x16x32_bf16(a0, w, acc[0][nf], 0, 0, 0);
            acc[1][nf] = __builtin_amdgcn_mfma_f32_16x16x32_bf16(a1, w, acc[1][nf], 0, 0, 0);
        }
    }

    if constexpr (DIN == 64) __syncthreads();   // h1 rows overlap other waves' A1 rows

    // prefetch kk=0 weight fragments of GEMM2
    bf16x8 wpre2[8];
    #pragma unroll
    for (int nf = 0; nf < 8; nf++)
        wpre2[nf] = *(const bf16x8*)(w2p + ((size_t)(nf*64 + lane))*8);

    // epilogue1: BN+GELU -> h1 in LDS [128][128] swizzled (wave-private rows)
    #pragma unroll
    for (int m = 0; m < 2; m++){
        #pragma unroll
        for (int nf = 0; nf < 8; nf++){
            int col = nf*16 + r16;
            float mu = mulA[col], ad = addA[col];
            #pragma unroll
            for (int r = 0; r < 4; r++){
                int row = wv*32 + m*16 + kg*4 + r;
                float xg = gelu_fast(acc[m][nf][r]*mu + ad);
                int byte = (row*128 + col)*2 ^ ((row & 7) << 4);
                *(ushort*)((char*)lds + byte) = f2bf(xg);
            }
        }
    }

    // GEMM2 (K = 128)
    f32x4 acc2[2][8];
    #pragma unroll
    for (int m = 0; m < 2; m++)
        #pragma unroll
        for (int nf = 0; nf < 8; nf++) acc2[m][nf] = (f32x4){0.f,0.f,0.f,0.f};
    #pragma unroll
    for (int kk = 0; kk < 4; kk++){
        int ab0 = (arow*128 + kk*32 + kg*8)*2 ^ ((arow & 7) << 4);
        bf16x8 a0 = *(const bf16x8*)((const char*)lds + ab0);
        bf16x8 a1 = *(const bf16x8*)((const char*)lds + ab0 + 128*32);
        #pragma unroll
        for (int nf = 0; nf < 8; nf++){
            bf16x8 w = (kk == 0) ? wpre2[nf]
                     : *(const bf16x8*)(w2p + ((size_t)((kk*8 + nf)*64 + lane))*8);
            acc2[0][nf] = __builtin_amdgcn_mfma_f32_16x16x32_bf16(a0, w, acc2[0][nf], 0, 0, 0);
            acc2[1][nf] = __builtin_amdgcn_mfma_f32_16x16x32_bf16(a1, w, acc2[1][nf], 0, 0, 0);
        }
    }

    // epilogue2: BN+GELU -> LDS (wave-private rows)
    #pragma unroll
    for (int m = 0; m < 2; m++){
        #pragma unroll
        for (int nf = 0; nf < 8; nf++){
            int col = nf*16 + r16;
            float mu = mulB[col], ad = addB[col];
            #pragma unroll
            for (int r = 0; r < 4; r++){
                int row = wv*32 + m*16 + kg*4 + r;
                float xg = gelu_fast(acc2[m][nf][r]*mu + ad);
                int byte = (row*128 + col)*2 ^ ((row & 7) << 4);
                *(ushort*)((char*)lds + byte) = f2bf(xg);
            }
        }
    }
    __syncthreads();

    // coalesced 16B stores
    for (int idx = tid; idx < 128*16; idx += 256){
        int r = idx >> 4, c = idx & 15;
        if (row0 + r < n){
            int byte = (r*128 + c*8)*2 ^ ((r & 7) << 4);
            uint4 v = *(const uint4*)((const char*)lds + byte);
            *(uint4*)(hout + (size_t)(row0+r)*128 + c*8) = v;
        }
    }
}

// ---------------- pooling (also accumulates per-graph node counts) ----------------
__global__ __launch_bounds__(128) void pool_kernel(const ushort* __restrict__ h,
        const int* __restrict__ batch, float* __restrict__ pool,
        float* __restrict__ cnt, int n){
    int c = threadIdx.x;
    int n0 = blockIdx.x * 32;
    float run = 0.f;
    float runc = 0.f;
    int curg = -1;
    for (int t = 0; t < 32; ++t){
        int node = n0 + t;
        if (node >= n) break;
        int gph = batch[node];
        if (gph != curg){
            if (curg >= 0){
                atomicAdd(&pool[curg*128 + c], run);
                if (c == 0) atomicAdd(&cnt[curg], runc);
            }
            curg = gph; run = 0.f; runc = 0.f;
        }
        run += bf2f(h[(size_t)node*128 + c]);
        runc += 1.f;
    }
    if (curg >= 0){
        atomicAdd(&pool[curg*128 + c], run);
        if (c == 0) atomicAdd(&cnt[curg], runc);
    }
}

// ---------------- head: fc1 -> LN -> GELU -> +res -> fc2 (f32, exact gelu) ----------------
__global__ __launch_bounds__(128) void head_kernel(const float* __restrict__ pool,
        const float* __restrict__ cnt,
        const float* __restrict__ fc1w, const float* __restrict__ fc1b,
        const float* __restrict__ lng, const float* __restrict__ lnb,
        const float* __restrict__ fc2w, const float* __restrict__ fc2b,
        float* __restrict__ out, int G){
    __shared__ float p[128];
    __shared__ float q[128];
    __shared__ float red[128];
    int g = blockIdx.x, c = threadIdx.x;
    float inv = 1.0f / fmaxf(cnt[g], 1.0f);
    float pv = pool[g*128 + c] * inv;
    p[c] = pv;
    __syncthreads();
    float o = fc1b[c];
    for (int k = 0; k < 128; k++) o = fmaf(p[k], fc1w[k*128 + c], o);
    red[c] = o; __syncthreads();
    for (int s = 64; s > 0; s >>= 1){ if (c < s) red[c] += red[c+s]; __syncthreads(); }
    float mu = red[0] * (1.0f/128.0f);
    __syncthreads();
    float d = o - mu;
    red[c] = d*d; __syncthreads();
    for (int s = 64; s > 0; s >>= 1){ if (c < s) red[c] += red[c+s]; __syncthreads(); }
    float var = red[0] * (1.0f/128.0f);
    __syncthreads();
    float xn = d * rsqrtf(var + LN_EPS) * lng[c] + lnb[c];
    float qv = gelu_exact(xn) + pv;
    q[c] = qv;
    __syncthreads();
    if (c < 64){
        float a = fc2b[c];
        for (int k = 0; k < 128; k++) a = fmaf(q[k], fc2w[k*64 + c], a);
        out[g*64 + c] = a;
    }
}

// ---------------- launch ----------------
extern "C" void kernel_launch(void* const* d_in, const int* in_sizes, int n_in,
                              void* d_out, int out_size, void* d_ws, size_t ws_size,
                              hipStream_t stream){
    const float* x     = (const float*)d_in[0];
    const int*   ei    = (const int*)d_in[1];
    const int*   batch = (const int*)d_in[2];
    const float* in_g  = (const float*)d_in[3];
    const float* in_b  = (const float*)d_in[4];
    const float* in_m  = (const float*)d_in[5];
    const float* in_v  = (const float*)d_in[6];
    const float* eps0  = (const float*)d_in[7];
    const float* c0_w1 = (const float*)d_in[8];
    const float* c0_b1 = (const float*)d_in[9];
    const float* c0_g  = (const float*)d_in[10];
    const float* c0_bb = (const float*)d_in[11];
    const float* c0_m  = (const float*)d_in[12];
    const float* c0_v  = (const float*)d_in[13];
    const float* c0_w2 = (const float*)d_in[14];
    const float* c0_b2 = (const float*)d_in[15];
    const float* bn0_g = (const float*)d_in[16];
    const float* bn0_b = (const float*)d_in[17];
    const float* bn0_m = (const float*)d_in[18];
    const float* bn0_v = (const float*)d_in[19];
    const float* epsR  = (const float*)d_in[20];
    const float* cR_w1 = (const float*)d_in[21];
    const float* cR_b1 = (const float*)d_in[22];
    const float* cR_g  = (const float*)d_in[23];
    const float* cR_bb = (const float*)d_in[24];
    const float* cR_m  = (const float*)d_in[25];
    const float* cR_v  = (const float*)d_in[26];
    const float* cR_w2 = (const float*)d_in[27];
    const float* cR_b2 = (const float*)d_in[28];
    const float* bnR_g = (const float*)d_in[29];
    const float* bnR_b = (const float*)d_in[30];
    const float* bnR_m = (const float*)d_in[31];
    const float* bnR_v = (const float*)d_in[32];
    const float* fc1_w = (const float*)d_in[33];
    const float* fc1_b = (const float*)d_in[34];
    const float* ln_g  = (const float*)d_in[35];
    const float* ln_b  = (const float*)d_in[36];
    const float* fc2_w = (const float*)d_in[37];
    const float* fc2_b = (const float*)d_in[38];

    const int N = in_sizes[0] / 64;
    const int E = in_sizes[1] / 2;
    const int G = out_size / 64;
    const int NB = (N + 255) >> 8;
    const int* srcp = ei;
    const int* dstp = ei + E;

    char* ws = (char*)d_ws;
    size_t off = 0;
    auto alloc = [&](size_t bytes)->char*{
        char* p = ws + off;
        off = (off + bytes + 255) & ~(size_t)255;
        return p;
    };
    ushort* bufA   = (ushort*)alloc((size_t)N*128*2);
    ushort* bufB   = (ushort*)alloc((size_t)N*128*2);
    int*    rowptr = (int*)   alloc((size_t)(N+1)*4);
    int*    csrc   = (int*)   alloc((size_t)E*4);
    uint*   pairs  = (uint*)  alloc((size_t)E*4);
    int*    bcnt   = (int*)   alloc((size_t)1025*4);
    int*    boff   = (int*)   alloc((size_t)1025*4);
    int*    bcur   = (int*)   alloc((size_t)1024*4);
    float*  pool   = (float*) alloc((size_t)G*128*4);
    float*  cnt    = (float*) alloc((size_t)G*4);
    ushort* pw0_1  = (ushort*)alloc((size_t)64*128*2);
    ushort* pw0_2  = (ushort*)alloc((size_t)128*128*2);
    ushort* pwR_1  = (ushort*)alloc((size_t)2*128*128*2);
    ushort* pwR_2  = (ushort*)alloc((size_t)2*128*128*2);
    (void)ws_size; (void)n_in;

    // pack weights into MFMA fragment order (bf16)
    pack_w<<<(1024 + 255)/256, 256, 0, stream>>>(c0_w1, pw0_1, 64);
    pack_w<<<(2048 + 255)/256, 256, 0, stream>>>(c0_w2, pw0_2, 128);
    for (int l = 0; l < 2; l++){
        pack_w<<<(2048 + 255)/256, 256, 0, stream>>>(cR_w1 + (size_t)l*128*128, pwR_1 + (size_t)l*128*128, 128);
        pack_w<<<(2048 + 255)/256, 256, 0, stream>>>(cR_w2 + (size_t)l*128*128, pwR_2 + (size_t)l*128*128, 128);
    }

    // bucketed CSR build
    zero_i32<<<(NB + 255)/256, 256, 0, stream>>>(bcnt, NB);
    bucket_count<<<1024, 256, 0, stream>>>(dstp, bcnt, E, NB);
    bucket_scan<<<1, 1024, 0, stream>>>(bcnt, boff, bcur, NB, E);
    partition_kernel<<<(E + PCH-1)/PCH, 512, 0, stream>>>(srcp, dstp, bcur, pairs, E, NB);
    bucket_build<<<NB, 256, 0, stream>>>(pairs, boff, rowptr, csrc, N, E, NB);

    // input BN -> bufA (N x 64 bf16, row-major)
    bn_input<<<(N*16 + 255)/256, 256, 0, stream>>>(x, in_g, in_b, in_m, in_v, bufA, N*16);

    const int agg_blocks = (N + 3)/4;
    const int mlp_blocks = (N + 127)/128;

    // layer 0 (64 -> 128)
    agg_d64<<<agg_blocks, 256, 0, stream>>>(bufA, rowptr, csrc, eps0, 0, bufB, N);
    mlp_mfma<64><<<mlp_blocks, 256, 0, stream>>>(bufB,
        pw0_1, c0_b1, c0_g, c0_bb, c0_m, c0_v,
        pw0_2, c0_b2, bn0_g, bn0_b, bn0_m, bn0_v, bufA, N);

    // layers 1..2 (128 -> 128)
    for (int l = 0; l < 2; l++){
        agg_d128<<<agg_blocks, 256, 0, stream>>>(bufA, rowptr, csrc, epsR, l, bufB, N);
        mlp_mfma<128><<<mlp_blocks, 256, 0, stream>>>(bufB,
            pwR_1 + (size_t)l*128*128, cR_b1 + l*128, cR_g + l*128, cR_bb + l*128,
            cR_m + l*128, cR_v + l*128,
            pwR_2 + (size_t)l*128*128, cR_b2 + l*128, bnR_g + l*128, bnR_b + l*128,
            bnR_m + l*128, bnR_v + l*128, bufA, N);
    }

    // mean pool + head
    zero_f32<<<(G*128 + 255)/256, 256, 0, stream>>>(pool, G*128);
    zero_f32<<<(G + 255)/256, 256, 0, stream>>>(cnt, G);
    pool_kernel<<<(N + 31)/32, 128, 0, stream>>>(bufA, batch, pool, cnt, N);
    head_kernel<<<G, 128, 0, stream>>>(pool, cnt, fc1_w, fc1_b, ln_g, ln_b,
                                       fc2_w, fc2_b, (float*)d_out, G);
}